// Round 2
// baseline (43.149 us; speedup 1.0000x reference)
//
#include <hip/hip_runtime.h>
#include <math.h>

// Cox partial-likelihood loss, N = 16384 — O(N log N) via per-chunk sort.
//   T = |y|, E = (y > 0), theta = y_hat, e = exp(theta)
//   risk[i] = sum_j e[j] * (T[j] >= T[i])
//           = sum_{chunks c} suffixsum_c[lower_bound_c(T_i)]
//   loss = -mean((theta - log(risk)) * E)
//
// ws layout: float sortedT[N]  (per-chunk ascending T)
//            float sortedS[N]  (per-chunk inclusive suffix sums of e)
//            float terms[N]    (per-i loss terms)

#define CHUNK 256
#define LOG_CHUNK 8

// ---------- K1: per-chunk bitonic sort by T + suffix-scan of e ----------
__global__ void __launch_bounds__(CHUNK) cox_sort(
        const float* __restrict__ y_hat, const float* __restrict__ y,
        float* __restrict__ sortedT, float* __restrict__ sortedS) {
    __shared__ float sT[CHUNK];
    __shared__ float sE[CHUNK];
    const int tid = threadIdx.x;
    const int base = blockIdx.x * CHUNK;

    sT[tid] = fabsf(y[base + tid]);
    sE[tid] = expf(y_hat[base + tid]);
    __syncthreads();

    // canonical in-place bitonic sort, ascending by T (value sE rides along)
    for (int k = 2; k <= CHUNK; k <<= 1) {
        for (int j = k >> 1; j > 0; j >>= 1) {
            int ixj = tid ^ j;
            if (ixj > tid) {
                float t0 = sT[tid], t1 = sT[ixj];
                bool up = ((tid & k) == 0);
                if (up ? (t0 > t1) : (t0 < t1)) {
                    float e0 = sE[tid], e1 = sE[ixj];
                    sT[tid] = t1; sT[ixj] = t0;
                    sE[tid] = e1; sE[ixj] = e0;
                }
            }
            __syncthreads();
        }
    }

    // inclusive suffix sum of sE (distance doubling)
    for (int d = 1; d < CHUNK; d <<= 1) {
        float add = (tid + d < CHUNK) ? sE[tid + d] : 0.0f;
        __syncthreads();
        sE[tid] += add;
        __syncthreads();
    }

    sortedT[base + tid] = sT[tid];
    sortedS[base + tid] = sE[tid];
}

// ---------- K2: one wave per i; lane c binary-searches chunk c ----------
__global__ void __launch_bounds__(256) cox_search(
        const float* __restrict__ y_hat, const float* __restrict__ y,
        const float* __restrict__ sortedT, const float* __restrict__ sortedS,
        float* __restrict__ terms) {
    const int tid = threadIdx.x;
    const int c = tid & 63;                    // chunk index = lane
    const int i = blockIdx.x * 4 + (tid >> 6); // one wave per i
    const float Ti = fabsf(y[i]);

    const float* Tc = sortedT + (c << LOG_CHUNK);
    // branchless lower_bound: first pos with Tc[pos] >= Ti, pos in [0, CHUNK]
    int pos = 0;
    #pragma unroll
    for (int half = CHUNK >> 1; half >= 1; half >>= 1)
        if (Tc[pos + half - 1] < Ti) pos += half;
    if (Tc[pos] < Ti) pos += 1;

    float part = (pos < CHUNK) ? sortedS[(c << LOG_CHUNK) + pos] : 0.0f;

    // wave-64 reduce: risk_i = sum of 64 chunk partials
    #pragma unroll
    for (int off = 32; off >= 1; off >>= 1)
        part += __shfl_down(part, off, 64);

    if (c == 0) {
        float E = (y[i] > 0.0f) ? 1.0f : 0.0f;
        terms[i] = (y_hat[i] - logf(part)) * E;
    }
}

// ---------- K3: final reduction of 16384 terms -> scalar loss ----------
__global__ void __launch_bounds__(1024) cox_reduce(
        const float* __restrict__ terms, float* __restrict__ out, int n) {
    __shared__ float wsum[16];
    const int tid = threadIdx.x;
    float s = 0.0f;
    for (int k = tid; k < n; k += 1024) s += terms[k];
    #pragma unroll
    for (int off = 32; off >= 1; off >>= 1) s += __shfl_down(s, off, 64);
    if ((tid & 63) == 0) wsum[tid >> 6] = s;
    __syncthreads();
    if (tid < 16) {
        s = wsum[tid];
        #pragma unroll
        for (int off = 8; off >= 1; off >>= 1) s += __shfl_down(s, off, 64);
        if (tid == 0) out[0] = -s / (float)n;
    }
}

extern "C" void kernel_launch(void* const* d_in, const int* in_sizes, int n_in,
                              void* d_out, int out_size, void* d_ws, size_t ws_size,
                              hipStream_t stream) {
    const float* y_hat = (const float*)d_in[0];
    const float* y     = (const float*)d_in[1];
    float* out = (float*)d_out;
    const int n = in_sizes[0];   // 16384

    float* sortedT = (float*)d_ws;
    float* sortedS = sortedT + n;
    float* terms   = sortedS + n;

    cox_sort<<<n / CHUNK, CHUNK, 0, stream>>>(y_hat, y, sortedT, sortedS);
    cox_search<<<n / 4, 256, 0, stream>>>(y_hat, y, sortedT, sortedS, terms);
    cox_reduce<<<1, 1024, 0, stream>>>(terms, out, n);
}

// Round 3
// 35.312 us; speedup vs baseline: 1.2219x; 1.2219x over previous
//
#include <hip/hip_runtime.h>
#include <math.h>

// Cox partial-likelihood loss, N = 16384 — sorted-chunk suffix-sum scheme.
//   T = |y|, E = (y > 0), theta = y_hat, e = exp(theta)
//   risk[i] = sum_c  suffix_c[ lower_bound_c(T_i) ]   over 16 sorted chunks
//   loss = -mean((theta - log(risk)) * E)
//
// K0: 16 blocks x 1024 thr — per-chunk bitonic sort by T + inclusive suffix
//     sum of e -> sortedT[N], sortedS[N] in ws. Also zeroes out[0].
// K1: 64 blocks x 256 thr — stage sorted tables into LDS (two 64 KB passes),
//     each thread binary-searches all 16 chunks in LDS, computes its loss
//     term, block-reduces, one atomicAdd(out) per block.

#define CSZ     1024
#define NCH     16
#define BLK1    256
#define HALF_CH 8     // chunks staged per LDS pass (8 * 8 KB = 64 KB)

// ---------------- K0: per-chunk sort + suffix scan ----------------
__global__ void __launch_bounds__(CSZ) cox_sort(
        const float* __restrict__ y_hat, const float* __restrict__ y,
        float* __restrict__ sortedT, float* __restrict__ sortedS,
        float* __restrict__ out) {
    __shared__ float sT[CSZ];
    __shared__ float sE[CSZ];
    const int tid = threadIdx.x;
    const int base = blockIdx.x * CSZ;

    sT[tid] = fabsf(y[base + tid]);
    sE[tid] = expf(y_hat[base + tid]);
    if (base + tid == 0) out[0] = 0.0f;
    __syncthreads();

    // bitonic sort ascending by T, e rides along
    for (int k = 2; k <= CSZ; k <<= 1) {
        for (int j = k >> 1; j > 0; j >>= 1) {
            int ixj = tid ^ j;
            if (ixj > tid) {
                float t0 = sT[tid], t1 = sT[ixj];
                bool up = ((tid & k) == 0);
                if (up ? (t0 > t1) : (t0 < t1)) {
                    sT[tid] = t1; sT[ixj] = t0;
                    float e0 = sE[tid]; sE[tid] = sE[ixj]; sE[ixj] = e0;
                }
            }
            __syncthreads();
        }
    }

    // inclusive suffix sum of sE (Hillis–Steele doubling)
    for (int d = 1; d < CSZ; d <<= 1) {
        float add = (tid + d < CSZ) ? sE[tid + d] : 0.0f;
        __syncthreads();
        sE[tid] += add;
        __syncthreads();
    }

    sortedT[base + tid] = sT[tid];
    sortedS[base + tid] = sE[tid];
}

// ---------------- K1: LDS-resident search + fused loss reduce ----------------
__global__ void __launch_bounds__(BLK1) cox_search(
        const float* __restrict__ y_hat, const float* __restrict__ y,
        const float* __restrict__ sortedT, const float* __restrict__ sortedS,
        float* __restrict__ out, int n) {
    __shared__ float sTall[HALF_CH * CSZ];   // 32 KB
    __shared__ float sSall[HALF_CH * CSZ];   // 32 KB
    __shared__ float wsum[BLK1 / 64];

    const int tid = threadIdx.x;
    const int i = blockIdx.x * BLK1 + tid;
    const float Ti = fabsf(y[i]);

    float risk = 0.0f;

    for (int pass = 0; pass < 2; ++pass) {
        // wait for previous pass's readers before overwriting LDS
        __syncthreads();
        const float4* gT = (const float4*)(sortedT + pass * HALF_CH * CSZ);
        const float4* gS = (const float4*)(sortedS + pass * HALF_CH * CSZ);
        float4* lT = (float4*)sTall;
        float4* lS = (float4*)sSall;
        #pragma unroll
        for (int k = tid; k < HALF_CH * CSZ / 4; k += BLK1) {
            lT[k] = gT[k];
            lS[k] = gS[k];
        }
        __syncthreads();

        #pragma unroll
        for (int c = 0; c < HALF_CH; ++c) {
            const float* Tc = &sTall[c * CSZ];
            // branchless lower_bound in LDS: first pos with Tc[pos] >= Ti
            int pos = 0;
            #pragma unroll
            for (int half = CSZ >> 1; half >= 1; half >>= 1)
                if (Tc[pos + half - 1] < Ti) pos += half;
            if (Tc[pos] < Ti) pos += 1;
            risk += (pos < CSZ) ? sSall[c * CSZ + pos] : 0.0f;
        }
    }

    float E = (y[i] > 0.0f) ? 1.0f : 0.0f;
    float term = (y_hat[i] - logf(risk)) * E;

    // block reduce: wave-64 butterfly, then cross-wave via LDS
    #pragma unroll
    for (int off = 32; off >= 1; off >>= 1)
        term += __shfl_down(term, off, 64);
    if ((tid & 63) == 0) wsum[tid >> 6] = term;
    __syncthreads();
    if (tid == 0) {
        float s = wsum[0] + wsum[1] + wsum[2] + wsum[3];
        atomicAdd(out, -s / (float)n);
    }
}

extern "C" void kernel_launch(void* const* d_in, const int* in_sizes, int n_in,
                              void* d_out, int out_size, void* d_ws, size_t ws_size,
                              hipStream_t stream) {
    const float* y_hat = (const float*)d_in[0];
    const float* y     = (const float*)d_in[1];
    float* out = (float*)d_out;
    const int n = in_sizes[0];   // 16384

    float* sortedT = (float*)d_ws;
    float* sortedS = sortedT + n;

    cox_sort<<<n / CSZ, CSZ, 0, stream>>>(y_hat, y, sortedT, sortedS, out);
    cox_search<<<n / BLK1, BLK1, 0, stream>>>(y_hat, y, sortedT, sortedS, out, n);
}